// Round 16
// baseline (466.901 us; speedup 1.0000x reference)
//
#include <hip/hip_runtime.h>
#include <hip/hip_bf16.h>
#include <math.h>

// Problem dims
#define B_  64
#define T_  256
#define F_  128
#define H_  8
#define E_  1024   // F*H
#define NH_ 4
#define HD_ 256    // E/NH
#define D_  256

// output element offsets within d_out (element units of the storage dtype)
#define OFF_Y_  0L
#define OFF_FI_ 4194304L
#define OFF_IA_ 4210688L

typedef unsigned short u16;
typedef unsigned int   u32;
typedef short bf16x8 __attribute__((ext_vector_type(8)));
typedef float f32x4  __attribute__((ext_vector_type(4)));

__device__ __forceinline__ float bf2f(u16 u) {
  union { u32 u; float f; } x; x.u = ((u32)u) << 16; return x.f;
}
__device__ __forceinline__ u16 f2bf(float f) {
  union { float f; u32 u; } x; x.f = f;
  u32 r = (x.u + 0x7fffu + ((x.u >> 16) & 1u)) >> 16;
  return (u16)r;
}
__device__ __forceinline__ float gelu_exact(float v) {
  return 0.5f * v * (1.f + erff(v * 0.70710678118654752f));
}
__device__ __forceinline__ float sigmoidf_(float v) {
  return 1.f / (1.f + __expf(-v));
}
__device__ __forceinline__ float ldv(const void* p, long i, bool isf) {
  return isf ? ((const float*)p)[i] : bf2f(((const u16*)p)[i]);
}
__device__ __forceinline__ void stv(void* p, long i, float v, bool isf) {
  if (isf) ((float*)p)[i] = v;
  else ((u16*)p)[i] = f2bf(v);
}
// async global->LDS, 16B/lane: LDS dest = wave-uniform base + lane*16 (HW)
__device__ __forceinline__ void gld16(void* lds, const void* g) {
  __builtin_amdgcn_global_load_lds(
      (const __attribute__((address_space(1))) u32*)g,
      (__attribute__((address_space(3))) u32*)lds, 16, 0, 0);
}
#define MFMA_ __builtin_amdgcn_mfma_f32_16x16x32_bf16

// ---------------------------------------------------------------------------
// dtype detector (flag: 0 = bf16 storage, 1 = f32 storage)
// ---------------------------------------------------------------------------
__global__ void detect_dtype(const u16* __restrict__ x, u32* __restrict__ flag) {
  if (threadIdx.x == 0 && blockIdx.x == 0) {
    int good = 0;
    for (int i = 0; i < 512; ++i) {
      u16 v = x[i];
      int e = (v >> 7) & 0xFF;
      if (v == 0 || (e >= 100 && e <= 140)) ++good;
    }
    *flag = (good >= 450) ? 0u : 1u;
  }
}

// ---------------------------------------------------------------------------
// MLP-only prep: input-attention MLP, 2 rows/block (8192 blocks x 256 thr)
// ---------------------------------------------------------------------------
__global__ __launch_bounds__(256)
void mlp_prep(const void* __restrict__ x,
              const void* __restrict__ w1, const void* __restrict__ b1,
              const void* __restrict__ w2, const void* __restrict__ b2,
              const u32* __restrict__ flag,
              u16* __restrict__ xg, void* __restrict__ dout) {
  const bool isf = (*flag != 0);
  const int tid = threadIdx.x;
  const int sub = tid >> 7, t7 = tid & 127;
  const long row = (long)blockIdx.x * 2 + sub;
  __shared__ float xr[2][F_];
  __shared__ float hid4[2][4][32];
  __shared__ float hid[2][32];
  __shared__ float red[4];
  float xv = ldv(x, row * F_ + t7, isf);
  xr[sub][t7] = xv;
  __syncthreads();
  {
    const int g = t7 & 31, part = t7 >> 5;
    const int f0 = part * 32;
    float s = 0.f;
    #pragma unroll 8
    for (int f = 0; f < 32; ++f)
      s += xr[sub][f0 + f] * ldv(w1, (long)(f0 + f) * 32 + g, isf);
    hid4[sub][part][g] = s;
  }
  __syncthreads();
  if (t7 < 32)
    hid[sub][t7] = gelu_exact(ldv(b1, t7, isf) + hid4[sub][0][t7] + hid4[sub][1][t7]
                              + hid4[sub][2][t7] + hid4[sub][3][t7]);
  __syncthreads();
  float s = ldv(b2, t7, isf);
  #pragma unroll 8
  for (int j = 0; j < 32; ++j) s += hid[sub][j] * ldv(w2, j * F_ + t7, isf);
  float ia = sigmoidf_(s);
  stv(dout, OFF_IA_ + row * F_ + t7, ia, isf);
  xg[row * F_ + t7] = f2bf(ia * xv);
  float v = ia;
  for (int o = 32; o > 0; o >>= 1) v += __shfl_down(v, o);
  if ((tid & 63) == 0) red[tid >> 6] = v;
  __syncthreads();
  if (t7 == 0) stv(dout, OFF_FI_ + row, red[sub * 2] + red[sub * 2 + 1], isf);
}

// ---------------------------------------------------------------------------
// GRU + weight-prep merged launch (5140 blocks):
// [0,256): GRU bank (proven core). Remaining blocks: weight transposes + bias
// converts, backfilling CUs idle during the low-occupancy GRU scan.
// [256,3328+256): wtI 96x32 | then wtM 32x32 | wtO 8x32 | wtF1 16x8 | wtF2 8x16 | bias 20
// ---------------------------------------------------------------------------
__device__ __forceinline__ void do_transpose(const void* __restrict__ in,
                                             u16* __restrict__ out, int R, int C,
                                             int bx, int by, bool isf,
                                             float (*t)[33], int tid) {
  const int tx = tid & 31, ty0 = tid >> 5;
  const int c0 = bx * 32, r0 = by * 32;
  for (int i = ty0; i < 32; i += 8)
    t[i][tx] = ldv(in, (long)(r0 + i) * C + c0 + tx, isf);
  __syncthreads();
  for (int i = ty0; i < 32; i += 8)
    out[(long)(c0 + i) * R + r0 + tx] = f2bf(t[tx][i]);
}

__global__ __launch_bounds__(256)
void gru_prep(const u16* __restrict__ xg, const void* __restrict__ W_ih,
              const void* __restrict__ W_hh, const void* __restrict__ b_ih,
              const void* __restrict__ b_hh,
              const void* __restrict__ ipw, const void* __restrict__ mhw,
              const void* __restrict__ opw, const void* __restrict__ f1w,
              const void* __restrict__ f2w,
              const void* __restrict__ ipb, const void* __restrict__ mhb,
              const void* __restrict__ opb, const void* __restrict__ f1b,
              const void* __restrict__ f2b,
              const u32* __restrict__ flag,
              u16* __restrict__ gruo,
              u16* __restrict__ wtI, u16* __restrict__ wtM, u16* __restrict__ wtO,
              u16* __restrict__ wtF1, u16* __restrict__ wtF2,
              u16* __restrict__ biasa) {
  const bool isf = (*flag != 0);
  const int bid = blockIdx.x;
  const int tid = threadIdx.x;
  __shared__ __align__(16) float hbuf[32][8];
  __shared__ float tt[32][33];
  if (bid < 256) {
    // ---- GRU role ----
    const int ric = tid >> 3;
    const int j   = tid & 7;
    const int rec = bid * 32 + ric;
    const int b = rec >> 7, f = rec & 127;
    float whr[8], whz[8], whn[8];
    #pragma unroll
    for (int k = 0; k < 8; ++k) {
      whr[k] = ldv(W_hh, (long)f * 192 + j * 8 + k, isf);
      whz[k] = ldv(W_hh, (long)f * 192 + (8 + j) * 8 + k, isf);
      whn[k] = ldv(W_hh, (long)f * 192 + (16 + j) * 8 + k, isf);
    }
    const float wir = ldv(W_ih, f * 24 + j, isf);
    const float wiz = ldv(W_ih, f * 24 + 8 + j, isf);
    const float win = ldv(W_ih, f * 24 + 16 + j, isf);
    const float cbr = ldv(b_ih, f * 24 + j, isf) + ldv(b_hh, f * 24 + j, isf);
    const float cbz = ldv(b_ih, f * 24 + 8 + j, isf) + ldv(b_hh, f * 24 + 8 + j, isf);
    const float bin_ = ldv(b_ih, f * 24 + 16 + j, isf);
    const float bhn_ = ldv(b_hh, f * 24 + 16 + j, isf);
    float h[8];
    #pragma unroll
    for (int k = 0; k < 8; ++k) h[k] = 0.f;
    const u16* xp = xg + (long)b * T_ * F_ + f;
    u16* op = gruo + (long)b * T_ * E_ + f * 8 + j;
    float xv = bf2f(xp[0]);
    for (int t = 0; t < T_; ++t) {
      float xn = (t + 1 < T_) ? bf2f(xp[(t + 1) * F_]) : 0.f;
      float ar = fmaf(xv, wir, cbr);
      float az = fmaf(xv, wiz, cbz);
      float an = bhn_;
      #pragma unroll
      for (int k = 0; k < 8; ++k) {
        ar = fmaf(h[k], whr[k], ar);
        az = fmaf(h[k], whz[k], az);
        an = fmaf(h[k], whn[k], an);
      }
      const float r = sigmoidf_(ar);
      const float z = sigmoidf_(az);
      const float a = fmaf(r, an, fmaf(xv, win, bin_));
      const float e = __expf(2.f * a);
      const float n = 1.f - 2.f / (e + 1.f);
      const float hn = fmaf(z, h[j] - n, n);
      op[(long)t * E_] = f2bf(hn);
      hbuf[ric][j] = hn;
      f32x4 h0 = *(const f32x4*)&hbuf[ric][0];
      f32x4 h1 = *(const f32x4*)&hbuf[ric][4];
      h[0] = h0[0]; h[1] = h0[1]; h[2] = h0[2]; h[3] = h0[3];
      h[4] = h1[0]; h[5] = h1[1]; h[6] = h1[2]; h[7] = h1[3];
      xv = xn;
    }
  } else if (bid < 3328) {
    const int r = bid - 256;
    do_transpose(ipw, wtI, 1024, 3072, r % 96, r / 96, isf, tt, tid);
  } else if (bid < 4352) {
    const int r = bid - 3328;
    do_transpose(mhw, wtM, 1024, 1024, r % 32, r / 32, isf, tt, tid);
  } else if (bid < 4608) {
    const int r = bid - 4352;
    do_transpose(opw, wtO, 1024, 256, r % 8, r / 8, isf, tt, tid);
  } else if (bid < 4736) {
    const int r = bid - 4608;
    do_transpose(f1w, wtF1, 256, 512, r % 16, r / 16, isf, tt, tid);
  } else if (bid < 4864) {
    const int r = bid - 4736;
    do_transpose(f2w, wtF2, 512, 256, r % 8, r / 8, isf, tt, tid);
  } else {
    const int i = (bid - 4864) * 256 + tid;
    if (i < 5120) {
      const void* s; long off;
      if (i < 3072)      { s = ipb; off = i; }
      else if (i < 4096) { s = mhb; off = i - 3072; }
      else if (i < 4352) { s = opb; off = i - 4096; }
      else if (i < 4864) { s = f1b; off = i - 4352; }
      else               { s = f2b; off = i - 4864; }
      biasa[i] = f2bf(ldv(s, off, isf));
    }
  }
}

// ---------------------------------------------------------------------------
// bt-form MFMA GEMM v4: 128x128, BK=32 (16KB LDS -> more blocks/CU, m97
// regime), 2-way-aliased swizzle (free per m136): slot = chunk ^ ((row>>1)&3).
// Source col permuted, linear gld16 dest, un-permuted ds_read.
// ---------------------------------------------------------------------------
template <int EPI>
__global__ __launch_bounds__(256)
void gemm_bt(const u16* __restrict__ A, int lda,
             const u16* __restrict__ Bp, int ldb,
             u16* __restrict__ Cg, int ldc,
             const u16* __restrict__ bias,
             int K, int nbm) {
  const int bm = blockIdx.x % nbm, bn = blockIdx.x / nbm;
  const int w = threadIdx.x >> 6, lane = threadIdx.x & 63;
  __shared__ __align__(16) u16 As[128 * 32];
  __shared__ __align__(16) u16 Bs[128 * 32];
  const long m0 = (long)bm * 128, n0 = (long)bn * 128;
  const int wm = w >> 1, wn = w & 1;
  const int rr = lane >> 2;                                  // row in 16-slab
  const int csw = ((lane & 3) ^ ((lane >> 3) & 3)) * 8;      // swizzled src col
  f32x4 acc[4][4] = {};
  const int nk = K >> 5;
  const int lr = lane & 15, lq = lane >> 4;
  const int co = ((lq ^ ((lr >> 1) & 3)) << 3);              // un-swizzled read col
  for (int kt = 0; kt < nk; ++kt) {
    const int k0 = kt << 5;
    __syncthreads();
    #pragma unroll
    for (int c = 0; c < 2; ++c) {
      const int rb = w * 32 + c * 16;
      gld16((char*)As + rb * 64, A + (m0 + rb + rr) * (long)lda + k0 + csw);
      gld16((char*)Bs + rb * 64, Bp + (n0 + rb + rr) * (long)ldb + k0 + csw);
    }
    __syncthreads();
    bf16x8 af[4], bfv[4];
    #pragma unroll
    for (int i = 0; i < 4; ++i)
      af[i] = *(const bf16x8*)&As[(wm * 64 + i * 16 + lr) * 32 + co];
    #pragma unroll
    for (int i = 0; i < 4; ++i)
      bfv[i] = *(const bf16x8*)&Bs[(wn * 64 + i * 16 + lr) * 32 + co];
    #pragma unroll
    for (int i = 0; i < 4; ++i) {
      #pragma unroll
      for (int j = 0; j < 4; ++j)
        acc[i][j] = MFMA_(af[i], bfv[j], acc[i][j], 0, 0, 0);
    }
  }
  const int rq = lq * 4;
  #pragma unroll
  for (int j = 0; j < 4; ++j) {
    const long col = n0 + wn * 64 + j * 16 + lr;
    const float bv = (EPI >= 1) ? bf2f(bias[col]) : 0.f;
    #pragma unroll
    for (int i = 0; i < 4; ++i) {
      const long row0 = m0 + wm * 64 + i * 16 + rq;
      #pragma unroll
      for (int q = 0; q < 4; ++q)
        Cg[(row0 + q) * (long)ldc + col] = f2bf(acc[i][j][q] + bv);
    }
  }
}

// ---------------------------------------------------------------------------
// Fused attention (unchanged, passing)
// ---------------------------------------------------------------------------
__global__ __launch_bounds__(256)
void attn_fused(const u16* __restrict__ qkv, u16* __restrict__ ctx) {
  const int z = blockIdx.y, bb = z >> 2, hh = z & 3;
  const int w = threadIdx.x >> 6, lane = threadIdx.x & 63;
  const int tid = threadIdx.x;
  const long t0 = (long)blockIdx.x * 64;
  __shared__ __align__(16) u16 P1[10240];
  __shared__ __align__(16) u16 Pl[64 * 264];
  __shared__ __align__(16) u16 Vt[256 * 40];
  const u16* qb = qkv + (long)bb * T_ * 3 * E_ + hh * HD_;
  const u16* kb = qb + E_;
  const u16* vb = qb + 2 * E_;
  const int rr = lane >> 2, cc = lane & 3;
  const int lr = lane & 15, lq = lane >> 4, lk = lq * 8;
  f32x4 acc[16] = {};
  for (int kt = 0; kt < 8; ++kt) {
    const int k0 = kt * 32;
    __syncthreads();
    gld16((char*)P1 + w * 16 * 64, qb + (t0 + w * 16 + rr) * (3L * E_) + k0 + cc * 8);
    #pragma unroll
    for (int c = 0; c < 4; ++c) {
      const int rb = w * 64 + c * 16;
      gld16((char*)P1 + 4096 + rb * 64, kb + (long)(rb + rr) * (3L * E_) + k0 + cc * 8);
    }
    __syncthreads();
    bf16x8 aq = *(const bf16x8*)&P1[(w * 16 + lr) * 32 + lk];
    #pragma unroll
    for (int nt = 0; nt < 16; ++nt) {
      bf16x8 bk = *(const bf16x8*)&P1[2048 + (nt * 16 + lr) * 32 + lk];
      acc[nt] = MFMA_(aq, bk, acc[nt], 0, 0, 0);
    }
  }
  #pragma unroll
  for (int q = 0; q < 4; ++q) {
    float mx = -3.4e38f;
    #pragma unroll
    for (int nt = 0; nt < 16; ++nt) mx = fmaxf(mx, acc[nt][q]);
    mx = fmaxf(mx, __shfl_xor(mx, 1));
    mx = fmaxf(mx, __shfl_xor(mx, 2));
    mx = fmaxf(mx, __shfl_xor(mx, 4));
    mx = fmaxf(mx, __shfl_xor(mx, 8));
    float e[16], sum = 0.f;
    #pragma unroll
    for (int nt = 0; nt < 16; ++nt) {
      e[nt] = __expf((acc[nt][q] - mx) * 0.0625f);
      sum += e[nt];
    }
    sum += __shfl_xor(sum, 1);
    sum += __shfl_xor(sum, 2);
    sum += __shfl_xor(sum, 4);
    sum += __shfl_xor(sum, 8);
    const float inv = 1.f / sum;
    const int rowl = w * 16 + lq * 4 + q;
    #pragma unroll
    for (int nt = 0; nt < 16; ++nt)
      Pl[rowl * 264 + nt * 16 + lr] = f2bf(e[nt] * inv);
  }
  f32x4 acc2[16] = {};
  for (int st = 0; st < 8; ++st) {
    const int s0 = st * 32;
    __syncthreads();
    #pragma unroll
    for (int c = 0; c < 4; ++c) {
      const int rb = w * 8 + c * 2;
      gld16((char*)P1 + rb * 512, vb + (s0 + rb + (lane >> 5)) * (3L * E_) + (lane & 31) * 8);
    }
    __syncthreads();
    u16 col[32];
    #pragma unroll
    for (int si = 0; si < 32; ++si) col[si] = P1[si * 256 + tid];
    #pragma unroll
    for (int cq = 0; cq < 4; ++cq)
      *(uint4*)&Vt[tid * 40 + cq * 8] = *(const uint4*)&col[cq * 8];
    __syncthreads();
    bf16x8 pa = *(const bf16x8*)&Pl[(w * 16 + lr) * 264 + s0 + lk];
    #pragma unroll
    for (int nt = 0; nt < 16; ++nt) {
      bf16x8 bv = *(const bf16x8*)&Vt[(nt * 16 + lr) * 40 + lk];
      acc2[nt] = MFMA_(pa, bv, acc2[nt], 0, 0, 0);
    }
  }
  const int rq = lq * 4;
  #pragma unroll
  for (int nt = 0; nt < 16; ++nt) {
    const int cold = nt * 16 + lr;
    #pragma unroll
    for (int q = 0; q < 4; ++q) {
      const long row = t0 + w * 16 + rq + q;
      ctx[((long)bb * T_ + row) * E_ + hh * HD_ + cold] = f2bf(acc2[nt][q]);
    }
  }
}

// ---------------------------------------------------------------------------
// Fused tail (round-11 proven): per block, 32 M-rows through h1 -> ffh -> y.
// ---------------------------------------------------------------------------
__global__ __launch_bounds__(256)
void fused_tail(const u16* __restrict__ MHA,
                const u16* __restrict__ wtO, const u16* __restrict__ wtF1,
                const u16* __restrict__ wtF2,
                const u16* __restrict__ bO, const u16* __restrict__ bF1,
                const u16* __restrict__ bF2,
                void* __restrict__ Y, const u32* __restrict__ flag) {
  const bool isf = (*flag != 0);
  const int w = threadIdx.x >> 6, lane = threadIdx.x & 63;
  const long m0 = (long)blockIdx.x * 32;
  __shared__ __align__(16) u16 Astg[32 * 64];    // 4KB
  __shared__ __align__(16) u16 h1s[32 * 264];    // 16.5KB
  __shared__ __align__(16) u16 ffhs[32 * 520];   // 32.5KB
  const int lr = lane & 15, lq = lane >> 4;
  const int rq = lq * 4;
  const int srow = w * 8 + (lane >> 3);
  const int csw = ((lane & 7) ^ ((lane >> 3) & 7)) * 8;
  // ---- sub1: h1[32][256], wave w -> cols w*64..+64 ----
  f32x4 acc1[2][4] = {};
  for (int kt = 0; kt < 16; ++kt) {
    const int k0 = kt << 6;
    __syncthreads();
    gld16(&Astg[w * 512], MHA + (m0 + srow) * 1024L + k0 + csw);
    __syncthreads();
    #pragma unroll
    for (int kk = 0; kk < 2; ++kk) {
      const int ch = kk * 4 + lq;
      const int cof = ((ch ^ (lr & 7)) << 3);
      bf16x8 af[2];
      #pragma unroll
      for (int i = 0; i < 2; ++i)
        af[i] = *(const bf16x8*)&Astg[(i * 16 + lr) * 64 + cof];
      #pragma unroll
      for (int j = 0; j < 4; ++j) {
        const int n = w * 64 + j * 16 + lr;
        bf16x8 bfv = *(const bf16x8*)(wtO + n * 1024L + k0 + kk * 32 + lq * 8);
        #pragma unroll
        for (int i = 0; i < 2; ++i)
          acc1[i][j] = MFMA_(af[i], bfv, acc1[i][j], 0, 0, 0);
      }
    }
  }
  __syncthreads();
  #pragma unroll
  for (int j = 0; j < 4; ++j) {
    const int col = w * 64 + j * 16 + lr;
    const float bv = bf2f(bO[col]);
    #pragma unroll
    for (int i = 0; i < 2; ++i)
      #pragma unroll
      for (int q = 0; q < 4; ++q)
        h1s[(i * 16 + rq + q) * 264 + col] = f2bf(acc1[i][j][q] + bv);
  }
  __syncthreads();
  // ---- sub2: ffh[32][512] = gelu(h1 @ wtF1^T + bF1), wave w -> cols w*128 ----
  f32x4 acc2[2][8] = {};
  for (int kt = 0; kt < 8; ++kt) {
    const int k0 = kt << 5;
    bf16x8 af[2];
    #pragma unroll
    for (int i = 0; i < 2; ++i)
      af[i] = *(const bf16x8*)&h1s[(i * 16 + lr) * 264 + k0 + lq * 8];
    #pragma unroll
    for (int j = 0; j < 8; ++j) {
      const int n = w * 128 + j * 16 + lr;
      bf16x8 bfv = *(const bf16x8*)(wtF1 + n * 256L + k0 + lq * 8);
      #pragma unroll
      for (int i = 0; i < 2; ++i)
        acc2[i][j] = MFMA_(af[i], bfv, acc2[i][j], 0, 0, 0);
    }
  }
  __syncthreads();
  #pragma unroll
  for (int j = 0; j < 8; ++j) {
    const int col = w * 128 + j * 16 + lr;
    const float bv = bf2f(bF1[col]);
    #pragma unroll
    for (int i = 0; i < 2; ++i)
      #pragma unroll
      for (int q = 0; q < 4; ++q)
        ffhs[(i * 16 + rq + q) * 520 + col] = f2bf(gelu_exact(acc2[i][j][q] + bv));
  }
  __syncthreads();
  // ---- sub3: y[32][256] = h1 + ffh @ wtF2^T + bF2, wave w -> cols w*64 ----
  f32x4 acc3[2][4] = {};
  for (int kt = 0; kt < 16; ++kt) {
    const int k0 = kt << 5;
    bf16x8 af[2];
    #pragma unroll
    for (int i = 0; i < 2; ++i)
      af[i] = *(const bf16x8*)&ffhs[(i * 16 + lr) * 520 + k0 + lq * 8];
    #pragma unroll
    for (int j = 0; j < 4; ++j) {
      const int n = w * 64 + j * 16 + lr;
      bf16x8 bfv = *(const bf16x8*)(wtF2 + n * 512L + k0 + lq * 8);
      #pragma unroll
      for (int i = 0; i < 2; ++i)
        acc3[i][j] = MFMA_(af[i], bfv, acc3[i][j], 0, 0, 0);
    }
  }
  #pragma unroll
  for (int j = 0; j < 4; ++j) {
    const int col = w * 64 + j * 16 + lr;
    const float bv = bf2f(bF2[col]);
    #pragma unroll
    for (int i = 0; i < 2; ++i)
      #pragma unroll
      for (int q = 0; q < 4; ++q) {
        const int rl = i * 16 + rq + q;
        const float v = acc3[i][j][q] + bv + bf2f(h1s[rl * 264 + col]);
        stv(Y, (m0 + rl) * 256L + col, v, isf);
      }
  }
}

// ---------------------------------------------------------------------------
extern "C" void kernel_launch(void* const* d_in, const int* in_sizes, int n_in,
                              void* d_out, int out_size, void* d_ws, size_t ws_size,
                              hipStream_t stream) {
  (void)in_sizes; (void)n_in; (void)out_size; (void)ws_size;
  char* ws = (char*)d_ws;
  // ws layout (bytes), peak 151MB (proven safe: round 2 wrote 165.7MB cleanly)
  u16* BIASA = (u16*)(ws + 0);
  u32* FLAG  = (u32*)(ws + 12288);
  u16* wtI   = (u16*)(ws + 65536);      // [3072][1024]
  u16* wtM   = (u16*)(ws + 6356992);    // [1024][1024]
  u16* wtO   = (u16*)(ws + 8454144);    // [256][1024]
  u16* wtF1  = (u16*)(ws + 8978432);    // [512][256]
  u16* wtF2  = (u16*)(ws + 9240576);    // [256][512]
  u16* XG    = (u16*)(ws + 9502720);    // [B,T,F]
  u16* GRUO  = (u16*)(ws + 16777216);   // [B,T,E] (dead after QKV gemm)
  u16* CTX   = GRUO;                    // [B,T,E] overlay
  u16* QKV   = (u16*)(ws + 50331648);   // [B,T,3E] (dead after attn)
  u16* MHA   = (u16*)(ws + 50331648);   // [B,T,E] overlay on dead QKV

  detect_dtype<<<1, 64, 0, stream>>>((const u16*)d_in[0], FLAG);
  mlp_prep<<<8192, 256, 0, stream>>>(d_in[0], d_in[1], d_in[2], d_in[3], d_in[4],
                                     FLAG, XG, d_out);
  gru_prep<<<4884, 256, 0, stream>>>(
      XG, d_in[5], d_in[6], d_in[7], d_in[8],
      d_in[9], d_in[11], d_in[13], d_in[15], d_in[17],
      d_in[10], d_in[12], d_in[14], d_in[16], d_in[18],
      FLAG, GRUO, wtI, wtM, wtO, wtF1, wtF2, BIASA);

  // qkv = gruo @ in_proj + b   (M=16384, N=3072, K=1024)
  gemm_bt<1><<<dim3(128 * 24, 1), 256, 0, stream>>>(GRUO, 1024, wtI, 1024,
      QKV, 3072, BIASA, 1024, 128);
  // fused attention -> CTX [B,T,E]
  attn_fused<<<dim3(4, B_ * NH_), 256, 0, stream>>>(QKV, CTX);
  // mha = ctx @ mha_out_w + b  (M=16384, N=1024, K=1024)
  gemm_bt<1><<<dim3(128 * 8, 1), 256, 0, stream>>>(CTX, 1024, wtM, 1024,
      MHA, 1024, BIASA + 3072, 1024, 128);
  // fused tail: h1 -> ffh -> y (final output, dtype-flagged)
  fused_tail<<<512, 256, 0, stream>>>(MHA, wtO, wtF1, wtF2,
      BIASA + 4096, BIASA + 4352, BIASA + 4864, d_out, FLAG);
}

// Round 17
// 423.254 us; speedup vs baseline: 1.1031x; 1.1031x over previous
//
#include <hip/hip_runtime.h>
#include <hip/hip_bf16.h>
#include <math.h>

// Problem dims
#define B_  64
#define T_  256
#define F_  128
#define H_  8
#define E_  1024   // F*H
#define NH_ 4
#define HD_ 256    // E/NH
#define D_  256

// output element offsets within d_out (element units of the storage dtype)
#define OFF_Y_  0L
#define OFF_FI_ 4194304L
#define OFF_IA_ 4210688L

typedef unsigned short u16;
typedef unsigned int   u32;
typedef short bf16x8 __attribute__((ext_vector_type(8)));
typedef float f32x4  __attribute__((ext_vector_type(4)));

__device__ __forceinline__ float bf2f(u16 u) {
  union { u32 u; float f; } x; x.u = ((u32)u) << 16; return x.f;
}
__device__ __forceinline__ u16 f2bf(float f) {
  union { float f; u32 u; } x; x.f = f;
  u32 r = (x.u + 0x7fffu + ((x.u >> 16) & 1u)) >> 16;
  return (u16)r;
}
__device__ __forceinline__ float gelu_exact(float v) {
  return 0.5f * v * (1.f + erff(v * 0.70710678118654752f));
}
__device__ __forceinline__ float sigmoidf_(float v) {
  return 1.f / (1.f + __expf(-v));
}
__device__ __forceinline__ float ldv(const void* p, long i, bool isf) {
  return isf ? ((const float*)p)[i] : bf2f(((const u16*)p)[i]);
}
__device__ __forceinline__ void stv(void* p, long i, float v, bool isf) {
  if (isf) ((float*)p)[i] = v;
  else ((u16*)p)[i] = f2bf(v);
}
// async global->LDS, 16B/lane: LDS dest = wave-uniform base + lane*16 (HW)
__device__ __forceinline__ void gld16(void* lds, const void* g) {
  __builtin_amdgcn_global_load_lds(
      (const __attribute__((address_space(1))) u32*)g,
      (__attribute__((address_space(3))) u32*)lds, 16, 0, 0);
}
#define MFMA_ __builtin_amdgcn_mfma_f32_16x16x32_bf16

// ---------------------------------------------------------------------------
// dtype detector (flag: 0 = bf16 storage, 1 = f32 storage)
// ---------------------------------------------------------------------------
__global__ void detect_dtype(const u16* __restrict__ x, u32* __restrict__ flag) {
  if (threadIdx.x == 0 && blockIdx.x == 0) {
    int good = 0;
    for (int i = 0; i < 512; ++i) {
      u16 v = x[i];
      int e = (v >> 7) & 0xFF;
      if (v == 0 || (e >= 100 && e <= 140)) ++good;
    }
    *flag = (good >= 450) ? 0u : 1u;
  }
}

// ---------------------------------------------------------------------------
// MLP-only prep: input-attention MLP, 2 rows/block (8192 blocks x 256 thr)
// ---------------------------------------------------------------------------
__global__ __launch_bounds__(256)
void mlp_prep(const void* __restrict__ x,
              const void* __restrict__ w1, const void* __restrict__ b1,
              const void* __restrict__ w2, const void* __restrict__ b2,
              const u32* __restrict__ flag,
              u16* __restrict__ xg, void* __restrict__ dout) {
  const bool isf = (*flag != 0);
  const int tid = threadIdx.x;
  const int sub = tid >> 7, t7 = tid & 127;
  const long row = (long)blockIdx.x * 2 + sub;
  __shared__ float xr[2][F_];
  __shared__ float hid4[2][4][32];
  __shared__ float hid[2][32];
  __shared__ float red[4];
  float xv = ldv(x, row * F_ + t7, isf);
  xr[sub][t7] = xv;
  __syncthreads();
  {
    const int g = t7 & 31, part = t7 >> 5;
    const int f0 = part * 32;
    float s = 0.f;
    #pragma unroll 8
    for (int f = 0; f < 32; ++f)
      s += xr[sub][f0 + f] * ldv(w1, (long)(f0 + f) * 32 + g, isf);
    hid4[sub][part][g] = s;
  }
  __syncthreads();
  if (t7 < 32)
    hid[sub][t7] = gelu_exact(ldv(b1, t7, isf) + hid4[sub][0][t7] + hid4[sub][1][t7]
                              + hid4[sub][2][t7] + hid4[sub][3][t7]);
  __syncthreads();
  float s = ldv(b2, t7, isf);
  #pragma unroll 8
  for (int j = 0; j < 32; ++j) s += hid[sub][j] * ldv(w2, j * F_ + t7, isf);
  float ia = sigmoidf_(s);
  stv(dout, OFF_IA_ + row * F_ + t7, ia, isf);
  xg[row * F_ + t7] = f2bf(ia * xv);
  float v = ia;
  for (int o = 32; o > 0; o >>= 1) v += __shfl_down(v, o);
  if ((tid & 63) == 0) red[tid >> 6] = v;
  __syncthreads();
  if (t7 == 0) stv(dout, OFF_FI_ + row, red[sub * 2] + red[sub * 2 + 1], isf);
}

// ---------------------------------------------------------------------------
// GRU + weight-prep merged launch (4884 blocks): [0,256) GRU; rest transposes
// + bias converts backfilling CUs idle during the low-occupancy GRU scan.
// ---------------------------------------------------------------------------
__device__ __forceinline__ void do_transpose(const void* __restrict__ in,
                                             u16* __restrict__ out, int R, int C,
                                             int bx, int by, bool isf,
                                             float (*t)[33], int tid) {
  const int tx = tid & 31, ty0 = tid >> 5;
  const int c0 = bx * 32, r0 = by * 32;
  for (int i = ty0; i < 32; i += 8)
    t[i][tx] = ldv(in, (long)(r0 + i) * C + c0 + tx, isf);
  __syncthreads();
  for (int i = ty0; i < 32; i += 8)
    out[(long)(c0 + i) * R + r0 + tx] = f2bf(t[tx][i]);
}

__global__ __launch_bounds__(256)
void gru_prep(const u16* __restrict__ xg, const void* __restrict__ W_ih,
              const void* __restrict__ W_hh, const void* __restrict__ b_ih,
              const void* __restrict__ b_hh,
              const void* __restrict__ ipw, const void* __restrict__ mhw,
              const void* __restrict__ opw, const void* __restrict__ f1w,
              const void* __restrict__ f2w,
              const void* __restrict__ ipb, const void* __restrict__ mhb,
              const void* __restrict__ opb, const void* __restrict__ f1b,
              const void* __restrict__ f2b,
              const u32* __restrict__ flag,
              u16* __restrict__ gruo,
              u16* __restrict__ wtI, u16* __restrict__ wtM, u16* __restrict__ wtO,
              u16* __restrict__ wtF1, u16* __restrict__ wtF2,
              u16* __restrict__ biasa) {
  const bool isf = (*flag != 0);
  const int bid = blockIdx.x;
  const int tid = threadIdx.x;
  __shared__ __align__(16) float hbuf[32][8];
  __shared__ float tt[32][33];
  if (bid < 256) {
    const int ric = tid >> 3;
    const int j   = tid & 7;
    const int rec = bid * 32 + ric;
    const int b = rec >> 7, f = rec & 127;
    float whr[8], whz[8], whn[8];
    #pragma unroll
    for (int k = 0; k < 8; ++k) {
      whr[k] = ldv(W_hh, (long)f * 192 + j * 8 + k, isf);
      whz[k] = ldv(W_hh, (long)f * 192 + (8 + j) * 8 + k, isf);
      whn[k] = ldv(W_hh, (long)f * 192 + (16 + j) * 8 + k, isf);
    }
    const float wir = ldv(W_ih, f * 24 + j, isf);
    const float wiz = ldv(W_ih, f * 24 + 8 + j, isf);
    const float win = ldv(W_ih, f * 24 + 16 + j, isf);
    const float cbr = ldv(b_ih, f * 24 + j, isf) + ldv(b_hh, f * 24 + j, isf);
    const float cbz = ldv(b_ih, f * 24 + 8 + j, isf) + ldv(b_hh, f * 24 + 8 + j, isf);
    const float bin_ = ldv(b_ih, f * 24 + 16 + j, isf);
    const float bhn_ = ldv(b_hh, f * 24 + 16 + j, isf);
    float h[8];
    #pragma unroll
    for (int k = 0; k < 8; ++k) h[k] = 0.f;
    const u16* xp = xg + (long)b * T_ * F_ + f;
    u16* op = gruo + (long)b * T_ * E_ + f * 8 + j;
    float xv = bf2f(xp[0]);
    for (int t = 0; t < T_; ++t) {
      float xn = (t + 1 < T_) ? bf2f(xp[(t + 1) * F_]) : 0.f;
      float ar = fmaf(xv, wir, cbr);
      float az = fmaf(xv, wiz, cbz);
      float an = bhn_;
      #pragma unroll
      for (int k = 0; k < 8; ++k) {
        ar = fmaf(h[k], whr[k], ar);
        az = fmaf(h[k], whz[k], az);
        an = fmaf(h[k], whn[k], an);
      }
      const float r = sigmoidf_(ar);
      const float z = sigmoidf_(az);
      const float a = fmaf(r, an, fmaf(xv, win, bin_));
      const float e = __expf(2.f * a);
      const float n = 1.f - 2.f / (e + 1.f);
      const float hn = fmaf(z, h[j] - n, n);
      op[(long)t * E_] = f2bf(hn);
      hbuf[ric][j] = hn;
      f32x4 h0 = *(const f32x4*)&hbuf[ric][0];
      f32x4 h1 = *(const f32x4*)&hbuf[ric][4];
      h[0] = h0[0]; h[1] = h0[1]; h[2] = h0[2]; h[3] = h0[3];
      h[4] = h1[0]; h[5] = h1[1]; h[6] = h1[2]; h[7] = h1[3];
      xv = xn;
    }
  } else if (bid < 3328) {
    const int r = bid - 256;
    do_transpose(ipw, wtI, 1024, 3072, r % 96, r / 96, isf, tt, tid);
  } else if (bid < 4352) {
    const int r = bid - 3328;
    do_transpose(mhw, wtM, 1024, 1024, r % 32, r / 32, isf, tt, tid);
  } else if (bid < 4608) {
    const int r = bid - 4352;
    do_transpose(opw, wtO, 1024, 256, r % 8, r / 8, isf, tt, tid);
  } else if (bid < 4736) {
    const int r = bid - 4608;
    do_transpose(f1w, wtF1, 256, 512, r % 16, r / 16, isf, tt, tid);
  } else if (bid < 4864) {
    const int r = bid - 4736;
    do_transpose(f2w, wtF2, 512, 256, r % 8, r / 8, isf, tt, tid);
  } else {
    const int i = (bid - 4864) * 256 + tid;
    if (i < 5120) {
      const void* s; long off;
      if (i < 3072)      { s = ipb; off = i; }
      else if (i < 4096) { s = mhb; off = i - 3072; }
      else if (i < 4352) { s = opb; off = i - 4096; }
      else if (i < 4864) { s = f1b; off = i - 4352; }
      else               { s = f2b; off = i - 4864; }
      biasa[i] = f2bf(ldv(s, off, isf));
    }
  }
}

// ---------------------------------------------------------------------------
// bt-form MFMA GEMM (round-14 proven core): 128x128, BK=64, swizzled gld16.
// ---------------------------------------------------------------------------
template <int EPI>
__global__ __launch_bounds__(256)
void gemm_bt(const u16* __restrict__ A, int lda,
             const u16* __restrict__ Bp, int ldb,
             u16* __restrict__ Cg, int ldc,
             const u16* __restrict__ bias,
             int K, int nbm) {
  const int bm = blockIdx.x % nbm, bn = blockIdx.x / nbm;
  const int w = threadIdx.x >> 6, lane = threadIdx.x & 63;
  __shared__ __align__(16) u16 As[128 * 64];
  __shared__ __align__(16) u16 Bs[128 * 64];
  const long m0 = (long)bm * 128, n0 = (long)bn * 128;
  const int wm = w >> 1, wn = w & 1;
  const int lr8 = lane >> 3;
  const int csw = ((lane & 7) ^ (lr8 & 7)) * 8;
  f32x4 acc[4][4] = {};
  const int nk = K >> 6;
  const int lr = lane & 15, lq = lane >> 4;
  for (int kt = 0; kt < nk; ++kt) {
    const int k0 = kt << 6;
    __syncthreads();
    #pragma unroll
    for (int c = 0; c < 4; ++c) {
      const int rb = w * 32 + c * 8;
      gld16((char*)As + rb * 128, A + (m0 + rb + lr8) * (long)lda + k0 + csw);
      gld16((char*)Bs + rb * 128, Bp + (n0 + rb + lr8) * (long)ldb + k0 + csw);
    }
    __syncthreads();
    #pragma unroll
    for (int sub = 0; sub < 2; ++sub) {
      const int ch = sub * 4 + lq;
      const int cof = ((ch ^ (lr & 7)) << 3);
      bf16x8 af[4], bfv[4];
      #pragma unroll
      for (int i = 0; i < 4; ++i)
        af[i] = *(const bf16x8*)&As[(wm * 64 + i * 16 + lr) * 64 + cof];
      #pragma unroll
      for (int i = 0; i < 4; ++i)
        bfv[i] = *(const bf16x8*)&Bs[(wn * 64 + i * 16 + lr) * 64 + cof];
      #pragma unroll
      for (int i = 0; i < 4; ++i) {
        #pragma unroll
        for (int j = 0; j < 4; ++j)
          acc[i][j] = MFMA_(af[i], bfv[j], acc[i][j], 0, 0, 0);
      }
    }
  }
  const int rq = lq * 4;
  #pragma unroll
  for (int j = 0; j < 4; ++j) {
    const long col = n0 + wn * 64 + j * 16 + lr;
    const float bv = (EPI >= 1) ? bf2f(bias[col]) : 0.f;
    #pragma unroll
    for (int i = 0; i < 4; ++i) {
      const long row0 = m0 + wm * 64 + i * 16 + rq;
      #pragma unroll
      for (int q = 0; q < 4; ++q)
        Cg[(row0 + q) * (long)ldc + col] = f2bf(acc[i][j][q] + bv);
    }
  }
}

// ---------------------------------------------------------------------------
// Fused attention (unchanged, passing)
// ---------------------------------------------------------------------------
__global__ __launch_bounds__(256)
void attn_fused(const u16* __restrict__ qkv, u16* __restrict__ ctx) {
  const int z = blockIdx.y, bb = z >> 2, hh = z & 3;
  const int w = threadIdx.x >> 6, lane = threadIdx.x & 63;
  const int tid = threadIdx.x;
  const long t0 = (long)blockIdx.x * 64;
  __shared__ __align__(16) u16 P1[10240];
  __shared__ __align__(16) u16 Pl[64 * 264];
  __shared__ __align__(16) u16 Vt[256 * 40];
  const u16* qb = qkv + (long)bb * T_ * 3 * E_ + hh * HD_;
  const u16* kb = qb + E_;
  const u16* vb = qb + 2 * E_;
  const int rr = lane >> 2, cc = lane & 3;
  const int lr = lane & 15, lq = lane >> 4, lk = lq * 8;
  f32x4 acc[16] = {};
  for (int kt = 0; kt < 8; ++kt) {
    const int k0 = kt * 32;
    __syncthreads();
    gld16((char*)P1 + w * 16 * 64, qb + (t0 + w * 16 + rr) * (3L * E_) + k0 + cc * 8);
    #pragma unroll
    for (int c = 0; c < 4; ++c) {
      const int rb = w * 64 + c * 16;
      gld16((char*)P1 + 4096 + rb * 64, kb + (long)(rb + rr) * (3L * E_) + k0 + cc * 8);
    }
    __syncthreads();
    bf16x8 aq = *(const bf16x8*)&P1[(w * 16 + lr) * 32 + lk];
    #pragma unroll
    for (int nt = 0; nt < 16; ++nt) {
      bf16x8 bk = *(const bf16x8*)&P1[2048 + (nt * 16 + lr) * 32 + lk];
      acc[nt] = MFMA_(aq, bk, acc[nt], 0, 0, 0);
    }
  }
  #pragma unroll
  for (int q = 0; q < 4; ++q) {
    float mx = -3.4e38f;
    #pragma unroll
    for (int nt = 0; nt < 16; ++nt) mx = fmaxf(mx, acc[nt][q]);
    mx = fmaxf(mx, __shfl_xor(mx, 1));
    mx = fmaxf(mx, __shfl_xor(mx, 2));
    mx = fmaxf(mx, __shfl_xor(mx, 4));
    mx = fmaxf(mx, __shfl_xor(mx, 8));
    float e[16], sum = 0.f;
    #pragma unroll
    for (int nt = 0; nt < 16; ++nt) {
      e[nt] = __expf((acc[nt][q] - mx) * 0.0625f);
      sum += e[nt];
    }
    sum += __shfl_xor(sum, 1);
    sum += __shfl_xor(sum, 2);
    sum += __shfl_xor(sum, 4);
    sum += __shfl_xor(sum, 8);
    const float inv = 1.f / sum;
    const int rowl = w * 16 + lq * 4 + q;
    #pragma unroll
    for (int nt = 0; nt < 16; ++nt)
      Pl[rowl * 264 + nt * 16 + lr] = f2bf(e[nt] * inv);
  }
  f32x4 acc2[16] = {};
  for (int st = 0; st < 8; ++st) {
    const int s0 = st * 32;
    __syncthreads();
    #pragma unroll
    for (int c = 0; c < 4; ++c) {
      const int rb = w * 8 + c * 2;
      gld16((char*)P1 + rb * 512, vb + (s0 + rb + (lane >> 5)) * (3L * E_) + (lane & 31) * 8);
    }
    __syncthreads();
    u16 col[32];
    #pragma unroll
    for (int si = 0; si < 32; ++si) col[si] = P1[si * 256 + tid];
    #pragma unroll
    for (int cq = 0; cq < 4; ++cq)
      *(uint4*)&Vt[tid * 40 + cq * 8] = *(const uint4*)&col[cq * 8];
    __syncthreads();
    bf16x8 pa = *(const bf16x8*)&Pl[(w * 16 + lr) * 264 + s0 + lk];
    #pragma unroll
    for (int nt = 0; nt < 16; ++nt) {
      bf16x8 bv = *(const bf16x8*)&Vt[(nt * 16 + lr) * 40 + lk];
      acc2[nt] = MFMA_(pa, bv, acc2[nt], 0, 0, 0);
    }
  }
  const int rq = lq * 4;
  #pragma unroll
  for (int nt = 0; nt < 16; ++nt) {
    const int cold = nt * 16 + lr;
    #pragma unroll
    for (int q = 0; q < 4; ++q) {
      const long row = t0 + w * 16 + rq + q;
      ctx[((long)bb * T_ + row) * E_ + hh * HD_ + cold] = f2bf(acc2[nt][q]);
    }
  }
}

// ---------------------------------------------------------------------------
// Fused tail (round-11 proven): per block, 32 M-rows through h1 -> ffh -> y.
// ---------------------------------------------------------------------------
__global__ __launch_bounds__(256)
void fused_tail(const u16* __restrict__ MHA,
                const u16* __restrict__ wtO, const u16* __restrict__ wtF1,
                const u16* __restrict__ wtF2,
                const u16* __restrict__ bO, const u16* __restrict__ bF1,
                const u16* __restrict__ bF2,
                void* __restrict__ Y, const u32* __restrict__ flag) {
  const bool isf = (*flag != 0);
  const int w = threadIdx.x >> 6, lane = threadIdx.x & 63;
  const long m0 = (long)blockIdx.x * 32;
  __shared__ __align__(16) u16 Astg[32 * 64];    // 4KB
  __shared__ __align__(16) u16 h1s[32 * 264];    // 16.5KB
  __shared__ __align__(16) u16 ffhs[32 * 520];   // 32.5KB
  const int lr = lane & 15, lq = lane >> 4;
  const int rq = lq * 4;
  const int srow = w * 8 + (lane >> 3);
  const int csw = ((lane & 7) ^ ((lane >> 3) & 7)) * 8;
  // ---- sub1: h1[32][256], wave w -> cols w*64..+64 ----
  f32x4 acc1[2][4] = {};
  for (int kt = 0; kt < 16; ++kt) {
    const int k0 = kt << 6;
    __syncthreads();
    gld16(&Astg[w * 512], MHA + (m0 + srow) * 1024L + k0 + csw);
    __syncthreads();
    #pragma unroll
    for (int kk = 0; kk < 2; ++kk) {
      const int ch = kk * 4 + lq;
      const int cof = ((ch ^ (lr & 7)) << 3);
      bf16x8 af[2];
      #pragma unroll
      for (int i = 0; i < 2; ++i)
        af[i] = *(const bf16x8*)&Astg[(i * 16 + lr) * 64 + cof];
      #pragma unroll
      for (int j = 0; j < 4; ++j) {
        const int n = w * 64 + j * 16 + lr;
        bf16x8 bfv = *(const bf16x8*)(wtO + n * 1024L + k0 + kk * 32 + lq * 8);
        #pragma unroll
        for (int i = 0; i < 2; ++i)
          acc1[i][j] = MFMA_(af[i], bfv, acc1[i][j], 0, 0, 0);
      }
    }
  }
  __syncthreads();
  #pragma unroll
  for (int j = 0; j < 4; ++j) {
    const int col = w * 64 + j * 16 + lr;
    const float bv = bf2f(bO[col]);
    #pragma unroll
    for (int i = 0; i < 2; ++i)
      #pragma unroll
      for (int q = 0; q < 4; ++q)
        h1s[(i * 16 + rq + q) * 264 + col] = f2bf(acc1[i][j][q] + bv);
  }
  __syncthreads();
  // ---- sub2: ffh[32][512] = gelu(h1 @ wtF1^T + bF1), wave w -> cols w*128 ----
  f32x4 acc2[2][8] = {};
  for (int kt = 0; kt < 8; ++kt) {
    const int k0 = kt << 5;
    bf16x8 af[2];
    #pragma unroll
    for (int i = 0; i < 2; ++i)
      af[i] = *(const bf16x8*)&h1s[(i * 16 + lr) * 264 + k0 + lq * 8];
    #pragma unroll
    for (int j = 0; j < 8; ++j) {
      const int n = w * 128 + j * 16 + lr;
      bf16x8 bfv = *(const bf16x8*)(wtF1 + n * 256L + k0 + lq * 8);
      #pragma unroll
      for (int i = 0; i < 2; ++i)
        acc2[i][j] = MFMA_(af[i], bfv, acc2[i][j], 0, 0, 0);
    }
  }
  __syncthreads();
  #pragma unroll
  for (int j = 0; j < 8; ++j) {
    const int col = w * 128 + j * 16 + lr;
    const float bv = bf2f(bF1[col]);
    #pragma unroll
    for (int i = 0; i < 2; ++i)
      #pragma unroll
      for (int q = 0; q < 4; ++q)
        ffhs[(i * 16 + rq + q) * 520 + col] = f2bf(gelu_exact(acc2[i][j][q] + bv));
  }
  __syncthreads();
  // ---- sub3: y[32][256] = h1 + ffh @ wtF2^T + bF2, wave w -> cols w*64 ----
  f32x4 acc3[2][4] = {};
  for (int kt = 0; kt < 16; ++kt) {
    const int k0 = kt << 5;
    bf16x8 af[2];
    #pragma unroll
    for (int i = 0; i < 2; ++i)
      af[i] = *(const bf16x8*)&ffhs[(i * 16 + lr) * 520 + k0 + lq * 8];
    #pragma unroll
    for (int j = 0; j < 4; ++j) {
      const int n = w * 64 + j * 16 + lr;
      bf16x8 bfv = *(const bf16x8*)(wtF2 + n * 512L + k0 + lq * 8);
      #pragma unroll
      for (int i = 0; i < 2; ++i)
        acc3[i][j] = MFMA_(af[i], bfv, acc3[i][j], 0, 0, 0);
    }
  }
  #pragma unroll
  for (int j = 0; j < 4; ++j) {
    const int col = w * 64 + j * 16 + lr;
    const float bv = bf2f(bF2[col]);
    #pragma unroll
    for (int i = 0; i < 2; ++i)
      #pragma unroll
      for (int q = 0; q < 4; ++q) {
        const int rl = i * 16 + rq + q;
        const float v = acc3[i][j][q] + bv + bf2f(h1s[rl * 264 + col]);
        stv(Y, (m0 + rl) * 256L + col, v, isf);
      }
  }
}

// ---------------------------------------------------------------------------
extern "C" void kernel_launch(void* const* d_in, const int* in_sizes, int n_in,
                              void* d_out, int out_size, void* d_ws, size_t ws_size,
                              hipStream_t stream) {
  (void)in_sizes; (void)n_in; (void)out_size; (void)ws_size;
  char* ws = (char*)d_ws;
  // ws layout (bytes), peak 151MB (proven safe: round 2 wrote 165.7MB cleanly)
  u16* BIASA = (u16*)(ws + 0);
  u32* FLAG  = (u32*)(ws + 12288);
  u16* wtI   = (u16*)(ws + 65536);      // [3072][1024]
  u16* wtM   = (u16*)(ws + 6356992);    // [1024][1024]
  u16* wtO   = (u16*)(ws + 8454144);    // [256][1024]
  u16* wtF1  = (u16*)(ws + 8978432);    // [512][256]
  u16* wtF2  = (u16*)(ws + 9240576);    // [256][512]
  u16* XG    = (u16*)(ws + 9502720);    // [B,T,F]
  u16* GRUO  = (u16*)(ws + 16777216);   // [B,T,E] (dead after QKV gemm)
  u16* CTX   = GRUO;                    // [B,T,E] overlay
  u16* QKV   = (u16*)(ws + 50331648);   // [B,T,3E] (dead after attn)
  u16* MHA   = (u16*)(ws + 50331648);   // [B,T,E] overlay on dead QKV

  detect_dtype<<<1, 64, 0, stream>>>((const u16*)d_in[0], FLAG);
  mlp_prep<<<8192, 256, 0, stream>>>(d_in[0], d_in[1], d_in[2], d_in[3], d_in[4],
                                     FLAG, XG, d_out);
  gru_prep<<<4884, 256, 0, stream>>>(
      XG, d_in[5], d_in[6], d_in[7], d_in[8],
      d_in[9], d_in[11], d_in[13], d_in[15], d_in[17],
      d_in[10], d_in[12], d_in[14], d_in[16], d_in[18],
      FLAG, GRUO, wtI, wtM, wtO, wtF1, wtF2, BIASA);

  // qkv = gruo @ in_proj + b   (M=16384, N=3072, K=1024)
  gemm_bt<1><<<dim3(128 * 24, 1), 256, 0, stream>>>(GRUO, 1024, wtI, 1024,
      QKV, 3072, BIASA, 1024, 128);
  // fused attention -> CTX [B,T,E]
  attn_fused<<<dim3(4, B_ * NH_), 256, 0, stream>>>(QKV, CTX);
  // mha = ctx @ mha_out_w + b  (M=16384, N=1024, K=1024)
  gemm_bt<1><<<dim3(128 * 8, 1), 256, 0, stream>>>(CTX, 1024, wtM, 1024,
      MHA, 1024, BIASA + 3072, 1024, 128);
  // fused tail: h1 -> ffh -> y (final output, dtype-flagged)
  fused_tail<<<512, 256, 0, stream>>>(MHA, wtO, wtF1, wtF2,
      BIASA + 4096, BIASA + 4352, BIASA + 4864, d_out, FLAG);
}

// Round 18
// 418.308 us; speedup vs baseline: 1.1162x; 1.0118x over previous
//
#include <hip/hip_runtime.h>
#include <hip/hip_bf16.h>
#include <math.h>

// Problem dims
#define B_  64
#define T_  256
#define F_  128
#define H_  8
#define E_  1024   // F*H
#define NH_ 4
#define HD_ 256    // E/NH
#define D_  256

// output element offsets within d_out (element units of the storage dtype)
#define OFF_Y_  0L
#define OFF_FI_ 4194304L
#define OFF_IA_ 4210688L

typedef unsigned short u16;
typedef unsigned int   u32;
typedef unsigned long long u64;
typedef short bf16x8 __attribute__((ext_vector_type(8)));
typedef float f32x4  __attribute__((ext_vector_type(4)));

__device__ __forceinline__ float bf2f(u16 u) {
  union { u32 u; float f; } x; x.u = ((u32)u) << 16; return x.f;
}
__device__ __forceinline__ u16 f2bf(float f) {
  union { float f; u32 u; } x; x.f = f;
  u32 r = (x.u + 0x7fffu + ((x.u >> 16) & 1u)) >> 16;
  return (u16)r;
}
__device__ __forceinline__ float gelu_exact(float v) {
  return 0.5f * v * (1.f + erff(v * 0.70710678118654752f));
}
__device__ __forceinline__ float sigmoidf_(float v) {
  return 1.f / (1.f + __expf(-v));
}
__device__ __forceinline__ float ldv(const void* p, long i, bool isf) {
  return isf ? ((const float*)p)[i] : bf2f(((const u16*)p)[i]);
}
__device__ __forceinline__ void stv(void* p, long i, float v, bool isf) {
  if (isf) ((float*)p)[i] = v;
  else ((u16*)p)[i] = f2bf(v);
}
// async global->LDS, 16B/lane: LDS dest = wave-uniform base + lane*16 (HW)
__device__ __forceinline__ void gld16(void* lds, const void* g) {
  __builtin_amdgcn_global_load_lds(
      (const __attribute__((address_space(1))) u32*)g,
      (__attribute__((address_space(3))) u32*)lds, 16, 0, 0);
}
#define MFMA_ __builtin_amdgcn_mfma_f32_16x16x32_bf16

// in-kernel dtype detect: wave lane samples probe[lane] (fixed 64-u16 window,
// L2-hot); bf16 storage -> ~64 plausible exponents, f32 -> ~37. isf = (<56).
__device__ __forceinline__ bool wave_detect_f32(const u16* probe, int lane) {
  u16 v = probe[lane];
  int e = (v >> 7) & 0xFF;
  bool plaus = (v == 0) || (e >= 100 && e <= 140);
  u64 m = __ballot(plaus);
  return __popcll(m) < 56;
}

// ---------------------------------------------------------------------------
// MLP prep: input-attention MLP, 2 rows/block (8192 blocks x 256 thr).
// Detects dtype locally; block 0 publishes FLAG for fused_tail.
// ---------------------------------------------------------------------------
__global__ __launch_bounds__(256)
void mlp_prep(const void* __restrict__ x,
              const void* __restrict__ w1, const void* __restrict__ b1,
              const void* __restrict__ w2, const void* __restrict__ b2,
              u32* __restrict__ flag,
              u16* __restrict__ xg, void* __restrict__ dout) {
  const int tid = threadIdx.x;
  __shared__ int isf_s;
  __shared__ float xr[2][F_];
  __shared__ float hid4[2][4][32];
  __shared__ float hid[2][32];
  __shared__ float red[4];
  if (tid < 64) {
    bool f = wave_detect_f32((const u16*)x, tid);
    if (tid == 0) {
      isf_s = f ? 1 : 0;
      if (blockIdx.x == 0) *flag = f ? 1u : 0u;
    }
  }
  __syncthreads();
  const bool isf = (isf_s != 0);
  const int sub = tid >> 7, t7 = tid & 127;
  const long row = (long)blockIdx.x * 2 + sub;
  float xv = ldv(x, row * F_ + t7, isf);
  xr[sub][t7] = xv;
  __syncthreads();
  {
    const int g = t7 & 31, part = t7 >> 5;
    const int f0 = part * 32;
    float s = 0.f;
    #pragma unroll 8
    for (int f = 0; f < 32; ++f)
      s += xr[sub][f0 + f] * ldv(w1, (long)(f0 + f) * 32 + g, isf);
    hid4[sub][part][g] = s;
  }
  __syncthreads();
  if (t7 < 32)
    hid[sub][t7] = gelu_exact(ldv(b1, t7, isf) + hid4[sub][0][t7] + hid4[sub][1][t7]
                              + hid4[sub][2][t7] + hid4[sub][3][t7]);
  __syncthreads();
  float s = ldv(b2, t7, isf);
  #pragma unroll 8
  for (int j = 0; j < 32; ++j) s += hid[sub][j] * ldv(w2, j * F_ + t7, isf);
  float ia = sigmoidf_(s);
  stv(dout, OFF_IA_ + row * F_ + t7, ia, isf);
  xg[row * F_ + t7] = f2bf(ia * xv);
  float v = ia;
  for (int o = 32; o > 0; o >>= 1) v += __shfl_down(v, o);
  if ((tid & 63) == 0) red[tid >> 6] = v;
  __syncthreads();
  if (t7 == 0) stv(dout, OFF_FI_ + row, red[sub * 2] + red[sub * 2 + 1], isf);
}

// ---------------------------------------------------------------------------
// GRU + weight-prep merged launch (4884 blocks): [0,256) GRU; rest transposes
// + bias converts backfilling CUs idle during the low-occupancy GRU scan.
// Detects dtype locally from W_hh[0..63].
// ---------------------------------------------------------------------------
__device__ __forceinline__ void do_transpose(const void* __restrict__ in,
                                             u16* __restrict__ out, int R, int C,
                                             int bx, int by, bool isf,
                                             float (*t)[33], int tid) {
  const int tx = tid & 31, ty0 = tid >> 5;
  const int c0 = bx * 32, r0 = by * 32;
  for (int i = ty0; i < 32; i += 8)
    t[i][tx] = ldv(in, (long)(r0 + i) * C + c0 + tx, isf);
  __syncthreads();
  for (int i = ty0; i < 32; i += 8)
    out[(long)(c0 + i) * R + r0 + tx] = f2bf(t[tx][i]);
}

__global__ __launch_bounds__(256)
void gru_prep(const u16* __restrict__ xg, const void* __restrict__ W_ih,
              const void* __restrict__ W_hh, const void* __restrict__ b_ih,
              const void* __restrict__ b_hh,
              const void* __restrict__ ipw, const void* __restrict__ mhw,
              const void* __restrict__ opw, const void* __restrict__ f1w,
              const void* __restrict__ f2w,
              const void* __restrict__ ipb, const void* __restrict__ mhb,
              const void* __restrict__ opb, const void* __restrict__ f1b,
              const void* __restrict__ f2b,
              u16* __restrict__ gruo,
              u16* __restrict__ wtI, u16* __restrict__ wtM, u16* __restrict__ wtO,
              u16* __restrict__ wtF1, u16* __restrict__ wtF2,
              u16* __restrict__ biasa) {
  const int bid = blockIdx.x;
  const int tid = threadIdx.x;
  __shared__ int isf_s;
  __shared__ __align__(16) float hbuf[32][8];
  __shared__ float tt[32][33];
  if (tid < 64) {
    bool f = wave_detect_f32((const u16*)W_hh, tid);
    if (tid == 0) isf_s = f ? 1 : 0;
  }
  __syncthreads();
  const bool isf = (isf_s != 0);
  if (bid < 256) {
    const int ric = tid >> 3;
    const int j   = tid & 7;
    const int rec = bid * 32 + ric;
    const int b = rec >> 7, f = rec & 127;
    float whr[8], whz[8], whn[8];
    #pragma unroll
    for (int k = 0; k < 8; ++k) {
      whr[k] = ldv(W_hh, (long)f * 192 + j * 8 + k, isf);
      whz[k] = ldv(W_hh, (long)f * 192 + (8 + j) * 8 + k, isf);
      whn[k] = ldv(W_hh, (long)f * 192 + (16 + j) * 8 + k, isf);
    }
    const float wir = ldv(W_ih, f * 24 + j, isf);
    const float wiz = ldv(W_ih, f * 24 + 8 + j, isf);
    const float win = ldv(W_ih, f * 24 + 16 + j, isf);
    const float cbr = ldv(b_ih, f * 24 + j, isf) + ldv(b_hh, f * 24 + j, isf);
    const float cbz = ldv(b_ih, f * 24 + 8 + j, isf) + ldv(b_hh, f * 24 + 8 + j, isf);
    const float bin_ = ldv(b_ih, f * 24 + 16 + j, isf);
    const float bhn_ = ldv(b_hh, f * 24 + 16 + j, isf);
    float h[8];
    #pragma unroll
    for (int k = 0; k < 8; ++k) h[k] = 0.f;
    const u16* xp = xg + (long)b * T_ * F_ + f;
    u16* op = gruo + (long)b * T_ * E_ + f * 8 + j;
    float xv = bf2f(xp[0]);
    for (int t = 0; t < T_; ++t) {
      float xn = (t + 1 < T_) ? bf2f(xp[(t + 1) * F_]) : 0.f;
      float ar = fmaf(xv, wir, cbr);
      float az = fmaf(xv, wiz, cbz);
      float an = bhn_;
      #pragma unroll
      for (int k = 0; k < 8; ++k) {
        ar = fmaf(h[k], whr[k], ar);
        az = fmaf(h[k], whz[k], az);
        an = fmaf(h[k], whn[k], an);
      }
      const float r = sigmoidf_(ar);
      const float z = sigmoidf_(az);
      const float a = fmaf(r, an, fmaf(xv, win, bin_));
      const float e = __expf(2.f * a);
      const float n = 1.f - 2.f / (e + 1.f);
      const float hn = fmaf(z, h[j] - n, n);
      op[(long)t * E_] = f2bf(hn);
      hbuf[ric][j] = hn;
      f32x4 h0 = *(const f32x4*)&hbuf[ric][0];
      f32x4 h1 = *(const f32x4*)&hbuf[ric][4];
      h[0] = h0[0]; h[1] = h0[1]; h[2] = h0[2]; h[3] = h0[3];
      h[4] = h1[0]; h[5] = h1[1]; h[6] = h1[2]; h[7] = h1[3];
      xv = xn;
    }
  } else if (bid < 3328) {
    const int r = bid - 256;
    do_transpose(ipw, wtI, 1024, 3072, r % 96, r / 96, isf, tt, tid);
  } else if (bid < 4352) {
    const int r = bid - 3328;
    do_transpose(mhw, wtM, 1024, 1024, r % 32, r / 32, isf, tt, tid);
  } else if (bid < 4608) {
    const int r = bid - 4352;
    do_transpose(opw, wtO, 1024, 256, r % 8, r / 8, isf, tt, tid);
  } else if (bid < 4736) {
    const int r = bid - 4608;
    do_transpose(f1w, wtF1, 256, 512, r % 16, r / 16, isf, tt, tid);
  } else if (bid < 4864) {
    const int r = bid - 4736;
    do_transpose(f2w, wtF2, 512, 256, r % 8, r / 8, isf, tt, tid);
  } else {
    const int i = (bid - 4864) * 256 + tid;
    if (i < 5120) {
      const void* s; long off;
      if (i < 3072)      { s = ipb; off = i; }
      else if (i < 4096) { s = mhb; off = i - 3072; }
      else if (i < 4352) { s = opb; off = i - 4096; }
      else if (i < 4864) { s = f1b; off = i - 4352; }
      else               { s = f2b; off = i - 4864; }
      biasa[i] = f2bf(ldv(s, off, isf));
    }
  }
}

// ---------------------------------------------------------------------------
// bt-form MFMA GEMM (round-14 proven core): 128x128, BK=64, swizzled gld16.
// ---------------------------------------------------------------------------
template <int EPI>
__global__ __launch_bounds__(256)
void gemm_bt(const u16* __restrict__ A, int lda,
             const u16* __restrict__ Bp, int ldb,
             u16* __restrict__ Cg, int ldc,
             const u16* __restrict__ bias,
             int K, int nbm) {
  const int bm = blockIdx.x % nbm, bn = blockIdx.x / nbm;
  const int w = threadIdx.x >> 6, lane = threadIdx.x & 63;
  __shared__ __align__(16) u16 As[128 * 64];
  __shared__ __align__(16) u16 Bs[128 * 64];
  const long m0 = (long)bm * 128, n0 = (long)bn * 128;
  const int wm = w >> 1, wn = w & 1;
  const int lr8 = lane >> 3;
  const int csw = ((lane & 7) ^ (lr8 & 7)) * 8;
  f32x4 acc[4][4] = {};
  const int nk = K >> 6;
  const int lr = lane & 15, lq = lane >> 4;
  for (int kt = 0; kt < nk; ++kt) {
    const int k0 = kt << 6;
    __syncthreads();
    #pragma unroll
    for (int c = 0; c < 4; ++c) {
      const int rb = w * 32 + c * 8;
      gld16((char*)As + rb * 128, A + (m0 + rb + lr8) * (long)lda + k0 + csw);
      gld16((char*)Bs + rb * 128, Bp + (n0 + rb + lr8) * (long)ldb + k0 + csw);
    }
    __syncthreads();
    #pragma unroll
    for (int sub = 0; sub < 2; ++sub) {
      const int ch = sub * 4 + lq;
      const int cof = ((ch ^ (lr & 7)) << 3);
      bf16x8 af[4], bfv[4];
      #pragma unroll
      for (int i = 0; i < 4; ++i)
        af[i] = *(const bf16x8*)&As[(wm * 64 + i * 16 + lr) * 64 + cof];
      #pragma unroll
      for (int i = 0; i < 4; ++i)
        bfv[i] = *(const bf16x8*)&Bs[(wn * 64 + i * 16 + lr) * 64 + cof];
      #pragma unroll
      for (int i = 0; i < 4; ++i) {
        #pragma unroll
        for (int j = 0; j < 4; ++j)
          acc[i][j] = MFMA_(af[i], bfv[j], acc[i][j], 0, 0, 0);
      }
    }
  }
  const int rq = lq * 4;
  #pragma unroll
  for (int j = 0; j < 4; ++j) {
    const long col = n0 + wn * 64 + j * 16 + lr;
    const float bv = (EPI >= 1) ? bf2f(bias[col]) : 0.f;
    #pragma unroll
    for (int i = 0; i < 4; ++i) {
      const long row0 = m0 + wm * 64 + i * 16 + rq;
      #pragma unroll
      for (int q = 0; q < 4; ++q)
        Cg[(row0 + q) * (long)ldc + col] = f2bf(acc[i][j][q] + bv);
    }
  }
}

// ---------------------------------------------------------------------------
// Fused attention (unchanged, passing)
// ---------------------------------------------------------------------------
__global__ __launch_bounds__(256)
void attn_fused(const u16* __restrict__ qkv, u16* __restrict__ ctx) {
  const int z = blockIdx.y, bb = z >> 2, hh = z & 3;
  const int w = threadIdx.x >> 6, lane = threadIdx.x & 63;
  const int tid = threadIdx.x;
  const long t0 = (long)blockIdx.x * 64;
  __shared__ __align__(16) u16 P1[10240];
  __shared__ __align__(16) u16 Pl[64 * 264];
  __shared__ __align__(16) u16 Vt[256 * 40];
  const u16* qb = qkv + (long)bb * T_ * 3 * E_ + hh * HD_;
  const u16* kb = qb + E_;
  const u16* vb = qb + 2 * E_;
  const int rr = lane >> 2, cc = lane & 3;
  const int lr = lane & 15, lq = lane >> 4, lk = lq * 8;
  f32x4 acc[16] = {};
  for (int kt = 0; kt < 8; ++kt) {
    const int k0 = kt * 32;
    __syncthreads();
    gld16((char*)P1 + w * 16 * 64, qb + (t0 + w * 16 + rr) * (3L * E_) + k0 + cc * 8);
    #pragma unroll
    for (int c = 0; c < 4; ++c) {
      const int rb = w * 64 + c * 16;
      gld16((char*)P1 + 4096 + rb * 64, kb + (long)(rb + rr) * (3L * E_) + k0 + cc * 8);
    }
    __syncthreads();
    bf16x8 aq = *(const bf16x8*)&P1[(w * 16 + lr) * 32 + lk];
    #pragma unroll
    for (int nt = 0; nt < 16; ++nt) {
      bf16x8 bk = *(const bf16x8*)&P1[2048 + (nt * 16 + lr) * 32 + lk];
      acc[nt] = MFMA_(aq, bk, acc[nt], 0, 0, 0);
    }
  }
  #pragma unroll
  for (int q = 0; q < 4; ++q) {
    float mx = -3.4e38f;
    #pragma unroll
    for (int nt = 0; nt < 16; ++nt) mx = fmaxf(mx, acc[nt][q]);
    mx = fmaxf(mx, __shfl_xor(mx, 1));
    mx = fmaxf(mx, __shfl_xor(mx, 2));
    mx = fmaxf(mx, __shfl_xor(mx, 4));
    mx = fmaxf(mx, __shfl_xor(mx, 8));
    float e[16], sum = 0.f;
    #pragma unroll
    for (int nt = 0; nt < 16; ++nt) {
      e[nt] = __expf((acc[nt][q] - mx) * 0.0625f);
      sum += e[nt];
    }
    sum += __shfl_xor(sum, 1);
    sum += __shfl_xor(sum, 2);
    sum += __shfl_xor(sum, 4);
    sum += __shfl_xor(sum, 8);
    const float inv = 1.f / sum;
    const int rowl = w * 16 + lq * 4 + q;
    #pragma unroll
    for (int nt = 0; nt < 16; ++nt)
      Pl[rowl * 264 + nt * 16 + lr] = f2bf(e[nt] * inv);
  }
  f32x4 acc2[16] = {};
  for (int st = 0; st < 8; ++st) {
    const int s0 = st * 32;
    __syncthreads();
    #pragma unroll
    for (int c = 0; c < 4; ++c) {
      const int rb = w * 8 + c * 2;
      gld16((char*)P1 + rb * 512, vb + (s0 + rb + (lane >> 5)) * (3L * E_) + (lane & 31) * 8);
    }
    __syncthreads();
    u16 col[32];
    #pragma unroll
    for (int si = 0; si < 32; ++si) col[si] = P1[si * 256 + tid];
    #pragma unroll
    for (int cq = 0; cq < 4; ++cq)
      *(uint4*)&Vt[tid * 40 + cq * 8] = *(const uint4*)&col[cq * 8];
    __syncthreads();
    bf16x8 pa = *(const bf16x8*)&Pl[(w * 16 + lr) * 264 + s0 + lk];
    #pragma unroll
    for (int nt = 0; nt < 16; ++nt) {
      bf16x8 bv = *(const bf16x8*)&Vt[(nt * 16 + lr) * 40 + lk];
      acc2[nt] = MFMA_(pa, bv, acc2[nt], 0, 0, 0);
    }
  }
  const int rq = lq * 4;
  #pragma unroll
  for (int nt = 0; nt < 16; ++nt) {
    const int cold = nt * 16 + lr;
    #pragma unroll
    for (int q = 0; q < 4; ++q) {
      const long row = t0 + w * 16 + rq + q;
      ctx[((long)bb * T_ + row) * E_ + hh * HD_ + cold] = f2bf(acc2[nt][q]);
    }
  }
}

// ---------------------------------------------------------------------------
// Fused tail (round-11 proven): per block, 32 M-rows through h1 -> ffh -> y.
// ---------------------------------------------------------------------------
__global__ __launch_bounds__(256)
void fused_tail(const u16* __restrict__ MHA,
                const u16* __restrict__ wtO, const u16* __restrict__ wtF1,
                const u16* __restrict__ wtF2,
                const u16* __restrict__ bO, const u16* __restrict__ bF1,
                const u16* __restrict__ bF2,
                void* __restrict__ Y, const u32* __restrict__ flag) {
  const bool isf = (*flag != 0);
  const int w = threadIdx.x >> 6, lane = threadIdx.x & 63;
  const long m0 = (long)blockIdx.x * 32;
  __shared__ __align__(16) u16 Astg[32 * 64];    // 4KB
  __shared__ __align__(16) u16 h1s[32 * 264];    // 16.5KB
  __shared__ __align__(16) u16 ffhs[32 * 520];   // 32.5KB
  const int lr = lane & 15, lq = lane >> 4;
  const int rq = lq * 4;
  const int srow = w * 8 + (lane >> 3);
  const int csw = ((lane & 7) ^ ((lane >> 3) & 7)) * 8;
  // ---- sub1: h1[32][256], wave w -> cols w*64..+64 ----
  f32x4 acc1[2][4] = {};
  for (int kt = 0; kt < 16; ++kt) {
    const int k0 = kt << 6;
    __syncthreads();
    gld16(&Astg[w * 512], MHA + (m0 + srow) * 1024L + k0 + csw);
    __syncthreads();
    #pragma unroll
    for (int kk = 0; kk < 2; ++kk) {
      const int ch = kk * 4 + lq;
      const int cof = ((ch ^ (lr & 7)) << 3);
      bf16x8 af[2];
      #pragma unroll
      for (int i = 0; i < 2; ++i)
        af[i] = *(const bf16x8*)&Astg[(i * 16 + lr) * 64 + cof];
      #pragma unroll
      for (int j = 0; j < 4; ++j) {
        const int n = w * 64 + j * 16 + lr;
        bf16x8 bfv = *(const bf16x8*)(wtO + n * 1024L + k0 + kk * 32 + lq * 8);
        #pragma unroll
        for (int i = 0; i < 2; ++i)
          acc1[i][j] = MFMA_(af[i], bfv, acc1[i][j], 0, 0, 0);
      }
    }
  }
  __syncthreads();
  #pragma unroll
  for (int j = 0; j < 4; ++j) {
    const int col = w * 64 + j * 16 + lr;
    const float bv = bf2f(bO[col]);
    #pragma unroll
    for (int i = 0; i < 2; ++i)
      #pragma unroll
      for (int q = 0; q < 4; ++q)
        h1s[(i * 16 + rq + q) * 264 + col] = f2bf(acc1[i][j][q] + bv);
  }
  __syncthreads();
  // ---- sub2: ffh[32][512] = gelu(h1 @ wtF1^T + bF1), wave w -> cols w*128 ----
  f32x4 acc2[2][8] = {};
  for (int kt = 0; kt < 8; ++kt) {
    const int k0 = kt << 5;
    bf16x8 af[2];
    #pragma unroll
    for (int i = 0; i < 2; ++i)
      af[i] = *(const bf16x8*)&h1s[(i * 16 + lr) * 264 + k0 + lq * 8];
    #pragma unroll
    for (int j = 0; j < 8; ++j) {
      const int n = w * 128 + j * 16 + lr;
      bf16x8 bfv = *(const bf16x8*)(wtF1 + n * 256L + k0 + lq * 8);
      #pragma unroll
      for (int i = 0; i < 2; ++i)
        acc2[i][j] = MFMA_(af[i], bfv, acc2[i][j], 0, 0, 0);
    }
  }
  __syncthreads();
  #pragma unroll
  for (int j = 0; j < 8; ++j) {
    const int col = w * 128 + j * 16 + lr;
    const float bv = bf2f(bF1[col]);
    #pragma unroll
    for (int i = 0; i < 2; ++i)
      #pragma unroll
      for (int q = 0; q < 4; ++q)
        ffhs[(i * 16 + rq + q) * 520 + col] = f2bf(gelu_exact(acc2[i][j][q] + bv));
  }
  __syncthreads();
  // ---- sub3: y[32][256] = h1 + ffh @ wtF2^T + bF2, wave w -> cols w*64 ----
  f32x4 acc3[2][4] = {};
  for (int kt = 0; kt < 16; ++kt) {
    const int k0 = kt << 5;
    bf16x8 af[2];
    #pragma unroll
    for (int i = 0; i < 2; ++i)
      af[i] = *(const bf16x8*)&ffhs[(i * 16 + lr) * 520 + k0 + lq * 8];
    #pragma unroll
    for (int j = 0; j < 4; ++j) {
      const int n = w * 64 + j * 16 + lr;
      bf16x8 bfv = *(const bf16x8*)(wtF2 + n * 512L + k0 + lq * 8);
      #pragma unroll
      for (int i = 0; i < 2; ++i)
        acc3[i][j] = MFMA_(af[i], bfv, acc3[i][j], 0, 0, 0);
    }
  }
  #pragma unroll
  for (int j = 0; j < 4; ++j) {
    const int col = w * 64 + j * 16 + lr;
    const float bv = bf2f(bF2[col]);
    #pragma unroll
    for (int i = 0; i < 2; ++i)
      #pragma unroll
      for (int q = 0; q < 4; ++q) {
        const int rl = i * 16 + rq + q;
        const float v = acc3[i][j][q] + bv + bf2f(h1s[rl * 264 + col]);
        stv(Y, (m0 + rl) * 256L + col, v, isf);
      }
  }
}

// ---------------------------------------------------------------------------
extern "C" void kernel_launch(void* const* d_in, const int* in_sizes, int n_in,
                              void* d_out, int out_size, void* d_ws, size_t ws_size,
                              hipStream_t stream) {
  (void)in_sizes; (void)n_in; (void)out_size; (void)ws_size;
  char* ws = (char*)d_ws;
  // ws layout (bytes), peak 151MB (proven safe: round 2 wrote 165.7MB cleanly)
  u16* BIASA = (u16*)(ws + 0);
  u32* FLAG  = (u32*)(ws + 12288);
  u16* wtI   = (u16*)(ws + 65536);      // [3072][1024]
  u16* wtM   = (u16*)(ws + 6356992);    // [1024][1024]
  u16* wtO   = (u16*)(ws + 8454144);    // [256][1024]
  u16* wtF1  = (u16*)(ws + 8978432);    // [512][256]
  u16* wtF2  = (u16*)(ws + 9240576);    // [256][512]
  u16* XG    = (u16*)(ws + 9502720);    // [B,T,F]
  u16* GRUO  = (u16*)(ws + 16777216);   // [B,T,E] (dead after QKV gemm)
  u16* CTX   = GRUO;                    // [B,T,E] overlay
  u16* QKV   = (u16*)(ws + 50331648);   // [B,T,3E] (dead after attn)
  u16* MHA   = (u16*)(ws + 50331648);   // [B,T,E] overlay on dead QKV

  mlp_prep<<<8192, 256, 0, stream>>>(d_in[0], d_in[1], d_in[2], d_in[3], d_in[4],
                                     FLAG, XG, d_out);
  gru_prep<<<4884, 256, 0, stream>>>(
      XG, d_in[5], d_in[6], d_in[7], d_in[8],
      d_in[9], d_in[11], d_in[13], d_in[15], d_in[17],
      d_in[10], d_in[12], d_in[14], d_in[16], d_in[18],
      GRUO, wtI, wtM, wtO, wtF1, wtF2, BIASA);

  // qkv = gruo @ in_proj + b   (M=16384, N=3072, K=1024)
  gemm_bt<1><<<dim3(128 * 24, 1), 256, 0, stream>>>(GRUO, 1024, wtI, 1024,
      QKV, 3072, BIASA, 1024, 128);
  // fused attention -> CTX [B,T,E]
  attn_fused<<<dim3(4, B_ * NH_), 256, 0, stream>>>(QKV, CTX);
  // mha = ctx @ mha_out_w + b  (M=16384, N=1024, K=1024)
  gemm_bt<1><<<dim3(128 * 8, 1), 256, 0, stream>>>(CTX, 1024, wtM, 1024,
      MHA, 1024, BIASA + 3072, 1024, 128);
  // fused tail: h1 -> ffh -> y (final output, dtype-flagged)
  fused_tail<<<512, 256, 0, stream>>>(MHA, wtO, wtF1, wtF2,
      BIASA + 4096, BIASA + 4352, BIASA + 4864, d_out, FLAG);
}